// Round 13
// baseline (4251.607 us; speedup 1.0000x reference)
//
#include <hip/hip_runtime.h>
#include <math.h>

// Sizes (fixed by the problem)
#define BATCH   64
#define SEQ     512
#define NIN     512
#define NHID    1024
#define NOUT    512

typedef short short8 __attribute__((ext_vector_type(8)));
typedef float f32x4 __attribute__((ext_vector_type(4)));
typedef float f32x4v __attribute__((ext_vector_type(4)));

// RNE fp32 -> bf16 bits
__device__ __forceinline__ unsigned short f2bf(float f) {
  unsigned int u = __float_as_uint(f);
  unsigned int r = (u + 0x7fffu + ((u >> 16) & 1u)) >> 16;
  return (unsigned short)r;
}

// ---------------- Tiled fp32 GEMM with bias (xi path, full fp32) --------
#define BM 128
#define BN 64
#define BK 16

__global__ __launch_bounds__(256) void gemm_bias(
    const float* __restrict__ A, const float* __restrict__ B,
    const float* __restrict__ bias, float* __restrict__ C,
    int M, int N, int K) {
  __shared__ float As[BK][BM + 4];
  __shared__ float Bs[BK][BN + 4];

  const int tid = threadIdx.x;
  const int bx = blockIdx.x;
  const int by = blockIdx.y;

  const int tm = (tid / 16) * 8;
  const int tn = (tid % 16) * 4;

  const int ar = tid / 4;
  const int ac = (tid % 4) * 4;
  const int br = tid / 16;
  const int bc = (tid % 16) * 4;

  float acc[8][4] = {};

  for (int k0 = 0; k0 < K; k0 += BK) {
    float4 av0 = *(const float4*)&A[(size_t)(by * BM + ar) * K + k0 + ac];
    float4 av1 = *(const float4*)&A[(size_t)(by * BM + ar + 64) * K + k0 + ac];
    As[ac + 0][ar] = av0.x;  As[ac + 0][ar + 64] = av1.x;
    As[ac + 1][ar] = av0.y;  As[ac + 1][ar + 64] = av1.y;
    As[ac + 2][ar] = av0.z;  As[ac + 2][ar + 64] = av1.z;
    As[ac + 3][ar] = av0.w;  As[ac + 3][ar + 64] = av1.w;
    float4 bv = *(const float4*)&B[(size_t)(k0 + br) * N + bx * BN + bc];
    *(float4*)&Bs[br][bc] = bv;
    __syncthreads();

#pragma unroll
    for (int k = 0; k < BK; ++k) {
      float4 a0 = *(const float4*)&As[k][tm];
      float4 a1 = *(const float4*)&As[k][tm + 4];
      float4 b4 = *(const float4*)&Bs[k][tn];
      float ae[8] = {a0.x, a0.y, a0.z, a0.w, a1.x, a1.y, a1.z, a1.w};
      float be[4] = {b4.x, b4.y, b4.z, b4.w};
#pragma unroll
      for (int i = 0; i < 8; ++i)
#pragma unroll
        for (int j = 0; j < 4; ++j)
          acc[i][j] = fmaf(ae[i], be[j], acc[i][j]);
    }
    __syncthreads();
  }

  const float4 bb = *(const float4*)&bias[bx * BN + tn];
#pragma unroll
  for (int i = 0; i < 8; ++i) {
    float4 o;
    o.x = acc[i][0] + bb.x;
    o.y = acc[i][1] + bb.y;
    o.z = acc[i][2] + bb.z;
    o.w = acc[i][3] + bb.w;
    *(float4*)&C[(size_t)(by * BM + tm + i) * N + bx * BN + tn] = o;
  }
}

// ---------------- bf16 MFMA GEMM with bias (output projection) ----------
// Validated r9: absmax 0.0156.
#define OBM 128
#define OBN 128
#define OBK 32
#define LDK 40

__global__ __launch_bounds__(256) void gemm_bias_bf16(
    const float* __restrict__ A, const float* __restrict__ B,
    const float* __restrict__ bias, float* __restrict__ C,
    int M, int N, int K) {
  __shared__ unsigned short Asb[OBM][LDK];
  __shared__ unsigned short Bsb[OBN][LDK];

  const int tid  = threadIdx.x;
  const int lane = tid & 63;
  const int wid  = tid >> 6;
  const int wm   = wid >> 1;
  const int wn   = wid & 1;
  const int bx   = blockIdx.x;
  const int by   = blockIdx.y;

  const int ar  = tid >> 1;
  const int aks = (tid & 1) * 16;
  const int bk4 = (tid >> 5) * 4;
  const int bn4 = (tid & 31) * 4;

  const int l15 = lane & 15;
  const int lk8 = (lane >> 4) * 8;

  f32x4 acc[4][4];
#pragma unroll
  for (int i = 0; i < 4; ++i)
#pragma unroll
    for (int j = 0; j < 4; ++j) acc[i][j] = (f32x4){0.f, 0.f, 0.f, 0.f};

  for (int k0 = 0; k0 < K; k0 += OBK) {
    const float* Ap = &A[(size_t)(by * OBM + ar) * K + k0 + aks];
    float4 a0 = *(const float4*)(Ap + 0);
    float4 a1 = *(const float4*)(Ap + 4);
    float4 a2 = *(const float4*)(Ap + 8);
    float4 a3 = *(const float4*)(Ap + 12);
    unsigned short ta[16] = {
        f2bf(a0.x), f2bf(a0.y), f2bf(a0.z), f2bf(a0.w),
        f2bf(a1.x), f2bf(a1.y), f2bf(a1.z), f2bf(a1.w),
        f2bf(a2.x), f2bf(a2.y), f2bf(a2.z), f2bf(a2.w),
        f2bf(a3.x), f2bf(a3.y), f2bf(a3.z), f2bf(a3.w)};
    *(short8*)&Asb[ar][aks + 0] = *(short8*)&ta[0];
    *(short8*)&Asb[ar][aks + 8] = *(short8*)&ta[8];

#pragma unroll
    for (int kk = 0; kk < 4; ++kk) {
      float4 bv = *(const float4*)&B[(size_t)(k0 + bk4 + kk) * N + bx * OBN + bn4];
      Bsb[bn4 + 0][bk4 + kk] = f2bf(bv.x);
      Bsb[bn4 + 1][bk4 + kk] = f2bf(bv.y);
      Bsb[bn4 + 2][bk4 + kk] = f2bf(bv.z);
      Bsb[bn4 + 3][bk4 + kk] = f2bf(bv.w);
    }
    __syncthreads();

    short8 afr[4], bfr[4];
#pragma unroll
    for (int t = 0; t < 4; ++t) {
      afr[t] = *(const short8*)&Asb[wm * 64 + t * 16 + l15][lk8];
      bfr[t] = *(const short8*)&Bsb[wn * 64 + t * 16 + l15][lk8];
    }
#pragma unroll
    for (int rt = 0; rt < 4; ++rt)
#pragma unroll
      for (int ct = 0; ct < 4; ++ct)
        acc[rt][ct] = __builtin_amdgcn_mfma_f32_16x16x32_bf16(
            afr[rt], bfr[ct], acc[rt][ct], 0, 0, 0);
    __syncthreads();
  }

#pragma unroll
  for (int rt = 0; rt < 4; ++rt) {
    const int row0 = by * OBM + wm * 64 + rt * 16 + (lane >> 4) * 4;
#pragma unroll
    for (int ct = 0; ct < 4; ++ct) {
      const int col = bx * OBN + wn * 64 + ct * 16 + l15;
      const float bb = bias[col];
#pragma unroll
      for (int i = 0; i < 4; ++i)
        C[(size_t)(row0 + i) * N + col] = acc[rt][ct][i] + bb;
    }
  }
}

// ---------------- Cooperative scan v13: L2-local exchange ---------------
// Fast path (groups co-located on one XCD — proven by r7's FETCH drop):
//   h + flags via PLAIN stores (land in the XCD-shared L2, ~200cy);
//   polls via sc0 loads (L1-bypass, L2-hit); staging via plain loads
//   (L2-hit). NO agent store ever touches an xi line (r8 lesson).
// Fallback (any mapping): every step also publishes h to an agent-scope
//   backup ring (2 slots, in d_out) + agent slowflags; the fast poll is
//   bounded (16K iters) and on timeout the group permanently switches to
//   the backup path. Deadlock-free, mapping-independent.
// L1 safety: only re-read global addresses are flags (always sc0) and
//   xin (always sc0). Staging/h-store addresses are fresh each step; a
//   block's own h stores in its L1 are the correct h values.
#define GROUPS 8
#define BPG    32
#define BPERG  8
#define POLL_BOUND 16384

#define FMA4(hv, wv4, accv)              \
  accv.x = fmaf(hv, wv4.x, accv.x);      \
  accv.y = fmaf(hv, wv4.y, accv.y);      \
  accv.z = fmaf(hv, wv4.z, accv.z);      \
  accv.w = fmaf(hv, wv4.w, accv.w);

__device__ __forceinline__ float load_sc0_f32(const float* p) {
  float v;
  asm volatile("global_load_dword %0, %1, off sc0\n\ts_waitcnt vmcnt(0)"
               : "=v"(v) : "v"(p) : "memory");
  __builtin_amdgcn_sched_barrier(0);
  return v;
}

__global__ __launch_bounds__(256, 1) void rnn_scan_ws(
    const float* __restrict__ Wh, float* __restrict__ xi,
    unsigned int* flags) {
  __shared__ float hs[BPERG * NHID];   // 32 KB staged h (also hn relay)
  __shared__ float P[256 * 32];        // 32 KB partial sums

  const int tid  = threadIdx.x;
  const int bg   = blockIdx.x & 7;    // XCD id under round-robin dispatch
  const int jc   = blockIdx.x >> 3;   // 0..31 column chunk
  const int c4   = tid & 7;
  const int kseg = tid >> 3;
  const int colbase = jc * 32 + c4 * 4;
  const int hswz  = (kseg & 7) << 2;
  const int stswz = ((tid >> 3) & 7) << 2;
  const int ob   = tid >> 5;
  const int ocol = tid & 31;
  const int oc4  = ocol >> 2;
  const int oce  = ocol & 3;

  float4 w[32];
#pragma unroll
  for (int kk = 0; kk < 32; ++kk)
    w[kk] = *(const float4*)&Wh[(size_t)(kseg * 32 + kk) * NHID + colbase];

  float* const xrow_base =
      xi + (size_t)(bg * BPERG + ob) * SEQ * NHID + jc * 32 + ocol;
  // Layout in d_out head: fastflags[256] @0, slowflags[256] @+1KB,
  // backup ring (2 x 64 x 1024 f32) @+2KB. All overwritten by out-GEMM.
  unsigned int* const fastflags = flags;
  unsigned int* const slowflags = flags + 256;
  float* const backup = (float*)(flags + 512);
  unsigned int* const myfast = fastflags + bg * 32 + jc;
  unsigned int* const myslow = slowflags + bg * 32 + jc;
  const unsigned int* const pollfast = fastflags + bg * 32 + (tid & 31);
  const unsigned int* const pollslow = slowflags + bg * 32 + (tid & 31);

  // backup element index for a thread-slot u (0..255) of this block
  // row = bg*8 + (u>>5), col = jc*32 + (u&31)
  const int bk_row_self = bg * BPERG + ob;
  const int bk_col_self = jc * 32 + ocol;

  bool sticky_slow = false;

  // xin for s=0: sc0 (L1-bypass; fills L2, which the later plain h store
  // to the same line will update coherently).
  float xin = load_sc0_f32(xrow_base);

  for (int s = 0; s < SEQ; ++s) {
    float4 acc[BPERG];
#pragma unroll
    for (int b = 0; b < BPERG; ++b) acc[b] = make_float4(0.f, 0.f, 0.f, 0.f);

    if (s > 0) {
      if (!sticky_slow) {
        // FAST staging: plain float4 loads — L2 hits on the dirty h lines.
        const float* base = xi + (size_t)(bg * BPERG) * SEQ * NHID +
                            (size_t)(s - 1) * NHID + tid * 4;
#pragma unroll
        for (int b = 0; b < BPERG; ++b) {
          float4 v = *(const float4*)(base + (size_t)b * SEQ * NHID);
          *(float4*)&hs[b * NHID + ((tid * 4) ^ stswz)] = v;
        }
      } else {
        // SLOW staging: bypassing loads from the agent backup ring.
        const float* bb = backup + ((size_t)((s - 1) & 1) * 64) * 1024 +
                          (size_t)(bg * BPERG) * 1024 + tid * 4;
        f32x4v bv[BPERG];
#pragma unroll
        for (int b = 0; b < BPERG; ++b) {
          asm volatile("global_load_dwordx4 %0, %1, off sc0 sc1"
                       : "=v"(bv[b]) : "v"(bb + (size_t)b * 1024) : "memory");
        }
        asm volatile("s_waitcnt vmcnt(0)" ::: "memory");
        __builtin_amdgcn_sched_barrier(0);
#pragma unroll
        for (int b = 0; b < BPERG; ++b) {
          float4 v;
          v.x = bv[b][0]; v.y = bv[b][1]; v.z = bv[b][2]; v.w = bv[b][3];
          *(float4*)&hs[b * NHID + ((tid * 4) ^ stswz)] = v;
        }
      }
      __syncthreads();

#pragma unroll
      for (int b = 0; b < BPERG; ++b) {
#pragma unroll
        for (int kq = 0; kq < 8; ++kq) {
          const float4 h4 =
              *(const float4*)&hs[b * NHID + kseg * 32 + ((kq * 4) ^ hswz)];
          FMA4(h4.x, w[kq * 4 + 0], acc[b]);
          FMA4(h4.y, w[kq * 4 + 1], acc[b]);
          FMA4(h4.z, w[kq * 4 + 2], acc[b]);
          FMA4(h4.w, w[kq * 4 + 3], acc[b]);
        }
      }
    }

    {
      const int u = kseg * 8 + c4;
      const int sw = (((kseg & 7) ^ c4)) << 2;
#pragma unroll
      for (int b = 0; b < BPERG; ++b)
        *(float4*)&P[u * 32 + ((b * 4) ^ sw)] = acc[b];
    }
    __syncthreads();

    float sum = 0.f;
#pragma unroll
    for (int q = 0; q < 32; ++q) {
      const int uu = q * 8 + oc4;
      const int sw2 = ((q & 7) ^ oc4) << 2;
      sum += P[uu * 32 + ((ob * 4 + oce) ^ sw2)];
    }

    const float hn = fmaxf(tanhf(xin + sum), 0.f);
    // Fast copy: PLAIN store -> shared L2 (also correct for the out-GEMM
    // via end-of-dispatch L2 flush).
    xi[(size_t)bk_row_self * SEQ * NHID + (size_t)s * NHID + bk_col_self] = hn;
    // Relay hn through LDS so wave0 (the poller) issues no backup stores.
    hs[tid] = hn;

    __syncthreads();  // drains plain h (~200cy); relay visible
    const unsigned int target = (unsigned int)(s + 1);
    if (tid == 0) *myfast = target;  // plain flag store -> shared L2

    // Backup publish (agent scope, off the fast critical path):
    // threads >=64 store their own element; threads 64..127 also store
    // wave0's relayed elements. Wave0 stores NOTHING (clean vmcnt for poll).
    {
      float* const bslot = backup + (size_t)(s & 1) * 64 * 1024;
      if (tid >= 64) {
        __hip_atomic_store(
            bslot + (size_t)bk_row_self * 1024 + bk_col_self, hn,
            __ATOMIC_RELAXED, __HIP_MEMORY_SCOPE_AGENT);
        if (tid < 128) {
          const int u = tid - 64;
          __hip_atomic_store(
              bslot + (size_t)(bg * BPERG + (u >> 5)) * 1024 + jc * 32 +
                  (u & 31),
              hs[u], __ATOMIC_RELAXED, __HIP_MEMORY_SCOPE_AGENT);
        }
      }
    }

    // Hoisted xin for s+1 (sc0; latency hides under the poll).
    if (s + 1 < SEQ)
      xin = load_sc0_f32(xrow_base + (size_t)(s + 1) * NHID);

    // ---- poll ----
    bool timedout = false;
    if (!sticky_slow) {
      if (tid < 64) {
        int it = 0;
        while (true) {
          unsigned int v;
          asm volatile("global_load_dword %0, %1, off sc0\n\ts_waitcnt vmcnt(0)"
                       : "=v"(v) : "v"(pollfast) : "memory");
          __builtin_amdgcn_sched_barrier(0);
          if (__all(v >= target)) break;
          if (++it >= POLL_BOUND) { timedout = true; break; }
          __builtin_amdgcn_s_sleep(1);
        }
      }
      // barrier + block-uniform decision (also drains backup stores of
      // threads >=64, which idle-waited here during the poll)
      if (__syncthreads_or((tid < 64) && timedout)) sticky_slow = true;
      else continue;  // fast path done for this step
    }

    // ---- slow path (recovery or sticky): publish + poll via MALL ----
    __syncthreads();  // ensure ALL backup stores drained (explicit)
    if (tid == 0)
      __hip_atomic_store(myslow, target, __ATOMIC_RELAXED,
                         __HIP_MEMORY_SCOPE_AGENT);
    if (tid < 64) {
      while (true) {
        unsigned int v;
        asm volatile(
            "global_load_dword %0, %1, off sc0 sc1\n\ts_waitcnt vmcnt(0)"
            : "=v"(v) : "v"(pollslow) : "memory");
        __builtin_amdgcn_sched_barrier(0);
        if (__all(v >= target)) break;
        __builtin_amdgcn_s_sleep(8);
      }
    }
    __syncthreads();
  }
}

extern "C" void kernel_launch(void* const* d_in, const int* in_sizes, int n_in,
                              void* d_out, int out_size, void* d_ws, size_t ws_size,
                              hipStream_t stream) {
  const float* x  = (const float*)d_in[0];  // [64,512,512]
  const float* Wi = (const float*)d_in[1];  // [512,1024]
  const float* bi = (const float*)d_in[2];  // [1024]
  const float* Wh = (const float*)d_in[3];  // [1024,1024]
  const float* Wo = (const float*)d_in[4];  // [1024,512]
  const float* bo = (const float*)d_in[5];  // [512]
  float* out = (float*)d_out;               // [64,512,512]
  float* xi  = (float*)d_ws;                // [64,512,1024] = 128 MB scratch

  // d_out head: fastflags 1KB + slowflags 1KB + backup ring 512KB.
  unsigned int* flags = (unsigned int*)d_out;

  const int M = BATCH * SEQ;  // 32768

  dim3 blk(256);
  hipMemsetAsync(flags, 0, 2048 + 2 * 64 * 1024 * sizeof(float), stream);
  // xi = x @ Wi + bi  (fp32 — feeds the recurrence)
  gemm_bias<<<dim3(NHID / BN, M / BM), blk, 0, stream>>>(x, Wi, bi, xi, M, NHID, NIN);
  // sequential scan (cooperative: all 256 blocks co-resident)
  {
    const float* Wh_p = Wh;
    float* xi_p = xi;
    unsigned int* flags_p = flags;
    void* args[3] = {(void*)&Wh_p, (void*)&xi_p, (void*)&flags_p};
    hipLaunchCooperativeKernel((const void*)rnn_scan_ws, dim3(GROUPS * BPG),
                               dim3(256), args, 0, stream);
  }
  // y = h @ Wo + bo  (bf16 MFMA, fp32 accumulate)
  gemm_bias_bf16<<<dim3(NOUT / OBN, M / OBM), blk, 0, stream>>>(xi, Wo, bo, out,
                                                               M, NOUT, NHID);
}

// Round 15
// 2466.504 us; speedup vs baseline: 1.7237x; 1.7237x over previous
//
#include <hip/hip_runtime.h>
#include <math.h>

// Sizes (fixed by the problem)
#define BATCH   64
#define SEQ     512
#define NIN     512
#define NHID    1024
#define NOUT    512

typedef short short8 __attribute__((ext_vector_type(8)));
typedef float f32x4 __attribute__((ext_vector_type(4)));

// RNE fp32 -> bf16 bits
__device__ __forceinline__ unsigned short f2bf(float f) {
  unsigned int u = __float_as_uint(f);
  unsigned int r = (u + 0x7fffu + ((u >> 16) & 1u)) >> 16;
  return (unsigned short)r;
}

#define GROUPS 8
#define BPG    32
#define BPERG  8

#define FMA4(hv, wv4, accv)              \
  accv.x = fmaf(hv, wv4.x, accv.x);      \
  accv.y = fmaf(hv, wv4.y, accv.y);      \
  accv.z = fmaf(hv, wv4.z, accv.z);      \
  accv.w = fmaf(hv, wv4.w, accv.w);

// ---------------- Tiled fp32 GEMM with bias (FALLBACK xi path) ----------
#define BM 128
#define BN 64
#define BK 16

__global__ __launch_bounds__(256) void gemm_bias(
    const float* __restrict__ A, const float* __restrict__ B,
    const float* __restrict__ bias, float* __restrict__ C,
    int M, int N, int K) {
  __shared__ float As[BK][BM + 4];
  __shared__ float Bs[BK][BN + 4];

  const int tid = threadIdx.x;
  const int bx = blockIdx.x;
  const int by = blockIdx.y;

  const int tm = (tid / 16) * 8;
  const int tn = (tid % 16) * 4;

  const int ar = tid / 4;
  const int ac = (tid % 4) * 4;
  const int br = tid / 16;
  const int bc = (tid % 16) * 4;

  float acc[8][4] = {};

  for (int k0 = 0; k0 < K; k0 += BK) {
    float4 av0 = *(const float4*)&A[(size_t)(by * BM + ar) * K + k0 + ac];
    float4 av1 = *(const float4*)&A[(size_t)(by * BM + ar + 64) * K + k0 + ac];
    As[ac + 0][ar] = av0.x;  As[ac + 0][ar + 64] = av1.x;
    As[ac + 1][ar] = av0.y;  As[ac + 1][ar + 64] = av1.y;
    As[ac + 2][ar] = av0.z;  As[ac + 2][ar + 64] = av1.z;
    As[ac + 3][ar] = av0.w;  As[ac + 3][ar + 64] = av1.w;
    float4 bv = *(const float4*)&B[(size_t)(k0 + br) * N + bx * BN + bc];
    *(float4*)&Bs[br][bc] = bv;
    __syncthreads();

#pragma unroll
    for (int k = 0; k < BK; ++k) {
      float4 a0 = *(const float4*)&As[k][tm];
      float4 a1 = *(const float4*)&As[k][tm + 4];
      float4 b4 = *(const float4*)&Bs[k][tn];
      float ae[8] = {a0.x, a0.y, a0.z, a0.w, a1.x, a1.y, a1.z, a1.w};
      float be[4] = {b4.x, b4.y, b4.z, b4.w};
#pragma unroll
      for (int i = 0; i < 8; ++i)
#pragma unroll
        for (int j = 0; j < 4; ++j)
          acc[i][j] = fmaf(ae[i], be[j], acc[i][j]);
    }
    __syncthreads();
  }

  const float4 bb = *(const float4*)&bias[bx * BN + tn];
#pragma unroll
  for (int i = 0; i < 8; ++i) {
    float4 o;
    o.x = acc[i][0] + bb.x;
    o.y = acc[i][1] + bb.y;
    o.z = acc[i][2] + bb.z;
    o.w = acc[i][3] + bb.w;
    *(float4*)&C[(size_t)(by * BM + tm + i) * N + bx * BN + tn] = o;
  }
}

// ---------------- bf16 MFMA GEMM with bias (output projection) ----------
// Validated r9/r12: absmax 0.0156.
#define OBM 128
#define OBN 128
#define OBK 32
#define LDK 40

__global__ __launch_bounds__(256) void gemm_bias_bf16(
    const float* __restrict__ A, const float* __restrict__ B,
    const float* __restrict__ bias, float* __restrict__ C,
    int M, int N, int K) {
  __shared__ unsigned short Asb[OBM][LDK];
  __shared__ unsigned short Bsb[OBN][LDK];

  const int tid  = threadIdx.x;
  const int lane = tid & 63;
  const int wid  = tid >> 6;
  const int wm   = wid >> 1;
  const int wn   = wid & 1;
  const int bx   = blockIdx.x;
  const int by   = blockIdx.y;

  const int ar  = tid >> 1;
  const int aks = (tid & 1) * 16;
  const int bk4 = (tid >> 5) * 4;
  const int bn4 = (tid & 31) * 4;

  const int l15 = lane & 15;
  const int lk8 = (lane >> 4) * 8;

  f32x4 acc[4][4];
#pragma unroll
  for (int i = 0; i < 4; ++i)
#pragma unroll
    for (int j = 0; j < 4; ++j) acc[i][j] = (f32x4){0.f, 0.f, 0.f, 0.f};

  for (int k0 = 0; k0 < K; k0 += OBK) {
    const float* Ap = &A[(size_t)(by * OBM + ar) * K + k0 + aks];
    float4 a0 = *(const float4*)(Ap + 0);
    float4 a1 = *(const float4*)(Ap + 4);
    float4 a2 = *(const float4*)(Ap + 8);
    float4 a3 = *(const float4*)(Ap + 12);
    unsigned short ta[16] = {
        f2bf(a0.x), f2bf(a0.y), f2bf(a0.z), f2bf(a0.w),
        f2bf(a1.x), f2bf(a1.y), f2bf(a1.z), f2bf(a1.w),
        f2bf(a2.x), f2bf(a2.y), f2bf(a2.z), f2bf(a2.w),
        f2bf(a3.x), f2bf(a3.y), f2bf(a3.z), f2bf(a3.w)};
    *(short8*)&Asb[ar][aks + 0] = *(short8*)&ta[0];
    *(short8*)&Asb[ar][aks + 8] = *(short8*)&ta[8];

#pragma unroll
    for (int kk = 0; kk < 4; ++kk) {
      float4 bv = *(const float4*)&B[(size_t)(k0 + bk4 + kk) * N + bx * OBN + bn4];
      Bsb[bn4 + 0][bk4 + kk] = f2bf(bv.x);
      Bsb[bn4 + 1][bk4 + kk] = f2bf(bv.y);
      Bsb[bn4 + 2][bk4 + kk] = f2bf(bv.z);
      Bsb[bn4 + 3][bk4 + kk] = f2bf(bv.w);
    }
    __syncthreads();

    short8 afr[4], bfr[4];
#pragma unroll
    for (int t = 0; t < 4; ++t) {
      afr[t] = *(const short8*)&Asb[wm * 64 + t * 16 + l15][lk8];
      bfr[t] = *(const short8*)&Bsb[wn * 64 + t * 16 + l15][lk8];
    }
#pragma unroll
    for (int rt = 0; rt < 4; ++rt)
#pragma unroll
      for (int ct = 0; ct < 4; ++ct)
        acc[rt][ct] = __builtin_amdgcn_mfma_f32_16x16x32_bf16(
            afr[rt], bfr[ct], acc[rt][ct], 0, 0, 0);
    __syncthreads();
  }

#pragma unroll
  for (int rt = 0; rt < 4; ++rt) {
    const int row0 = by * OBM + wm * 64 + rt * 16 + (lane >> 4) * 4;
#pragma unroll
    for (int ct = 0; ct < 4; ++ct) {
      const int col = bx * OBN + wn * 64 + ct * 16 + l15;
      const float bb = bias[col];
#pragma unroll
      for (int i = 0; i < 4; ++i)
        C[(size_t)(row0 + i) * N + col] = acc[rt][ct][i] + bb;
    }
  }
}

// ---------------- FALLBACK scan (r12 verbatim, proven 1.95 ms) ----------
__global__ __launch_bounds__(256, 1) void rnn_scan_ws(
    const float* __restrict__ Wh, float* __restrict__ xi,
    unsigned int* flags) {
  __shared__ float hs[BPERG * NHID];
  __shared__ float P[256 * 32];

  const int tid  = threadIdx.x;
  const int bg   = blockIdx.x & 7;
  const int jc   = blockIdx.x >> 3;
  const int c4   = tid & 7;
  const int kseg = tid >> 3;
  const int colbase = jc * 32 + c4 * 4;
  const int hswz  = (kseg & 7) << 2;
  const int stswz = ((tid >> 3) & 7) << 2;
  const int ob   = tid >> 5;
  const int ocol = tid & 31;
  const int oc4  = ocol >> 2;
  const int oce  = ocol & 3;

  float4 w[32];
#pragma unroll
  for (int kk = 0; kk < 32; ++kk)
    w[kk] = *(const float4*)&Wh[(size_t)(kseg * 32 + kk) * NHID + colbase];

  float* const xrow_base =
      xi + (size_t)(bg * BPERG + ob) * SEQ * NHID + jc * 32 + ocol;
  unsigned int* const gflags = flags + bg * 32;
  unsigned int* const myflag = gflags + jc;
  unsigned int* const pollflag = gflags + (tid & 31);

  float xin = __hip_atomic_load(xrow_base, __ATOMIC_RELAXED,
                                __HIP_MEMORY_SCOPE_AGENT);

  for (int s = 0; s < SEQ; ++s) {
    float* prow = xrow_base + (size_t)s * NHID;

    float4 acc[BPERG];
#pragma unroll
    for (int b = 0; b < BPERG; ++b) acc[b] = make_float4(0.f, 0.f, 0.f, 0.f);

    if (s > 0) {
      const float* base =
          xi + (size_t)(bg * BPERG) * SEQ * NHID + (size_t)(s - 1) * NHID + tid * 4;
#pragma unroll
      for (int b = 0; b < BPERG; ++b) {
        float4 v = *(const float4*)(base + (size_t)b * SEQ * NHID);
        *(float4*)&hs[b * NHID + ((tid * 4) ^ stswz)] = v;
      }
      __syncthreads();

#pragma unroll
      for (int b = 0; b < BPERG; ++b) {
#pragma unroll
        for (int kq = 0; kq < 8; ++kq) {
          const float4 h4 =
              *(const float4*)&hs[b * NHID + kseg * 32 + ((kq * 4) ^ hswz)];
          FMA4(h4.x, w[kq * 4 + 0], acc[b]);
          FMA4(h4.y, w[kq * 4 + 1], acc[b]);
          FMA4(h4.z, w[kq * 4 + 2], acc[b]);
          FMA4(h4.w, w[kq * 4 + 3], acc[b]);
        }
      }
    }

    {
      const int u = kseg * 8 + c4;
      const int sw = (((kseg & 7) ^ c4)) << 2;
#pragma unroll
      for (int b = 0; b < BPERG; ++b)
        *(float4*)&P[u * 32 + ((b * 4) ^ sw)] = acc[b];
    }
    __syncthreads();

    float sum = 0.f;
#pragma unroll
    for (int q = 0; q < 32; ++q) {
      const int uu = q * 8 + oc4;
      const int sw2 = ((q & 7) ^ oc4) << 2;
      sum += P[uu * 32 + ((ob * 4 + oce) ^ sw2)];
    }

    const float hn = fmaxf(tanhf(xin + sum), 0.f);
    __hip_atomic_store(prow, hn, __ATOMIC_RELAXED, __HIP_MEMORY_SCOPE_AGENT);

    __syncthreads();
    const unsigned int target = (unsigned int)(s + 1);
    if (tid == 0)
      __hip_atomic_store(myflag, target, __ATOMIC_RELAXED,
                         __HIP_MEMORY_SCOPE_AGENT);

    if (s + 1 < SEQ)
      xin = __hip_atomic_load(xrow_base + (size_t)(s + 1) * NHID,
                              __ATOMIC_RELAXED, __HIP_MEMORY_SCOPE_AGENT);

    if (tid < 64) {
      while (true) {
        unsigned int v = __hip_atomic_load(pollflag, __ATOMIC_RELAXED,
                                           __HIP_MEMORY_SCOPE_AGENT);
        if (__all(v >= target)) break;
        __builtin_amdgcn_s_sleep(1);
      }
    }
    __syncthreads();
  }
}

// ---------------- FUSED: scan (blocks 0..255) + xi workers (256..511) ---
// r14 structure with the REPLAY-RACE FIX: workers drain their inline-asm
// xi stores (explicit s_waitcnt vmcnt(0) — the compiler does NOT track asm
// stores, so __syncthreads alone does not wait for them) before bumping
// xi_done. Host side picks fused-vs-fallback via a DETERMINISTIC occupancy
// query (identical decision at correctness call, capture, and replay).
__global__ __launch_bounds__(256, 2) void rnn_fused(
    const float* __restrict__ Wh, const float* __restrict__ Wi,
    const float* __restrict__ x, const float* __restrict__ bi,
    float* __restrict__ xi, unsigned int* flags) {
  __shared__ float smem[16384];  // 64 KB, role-dependent layout
  const int tid = threadIdx.x;
  unsigned int* const xi_done = flags + 256;

  if (blockIdx.x >= GROUPS * BPG) {
    // ================= worker =================
    const int bw = blockIdx.x - GROUPS * BPG;  // 0..255
    float* As = smem;                // [16][132]
    float* Bs = smem + 16 * 132;     // [16][68]
    const int tm = (tid / 16) * 8;
    const int tn = (tid % 16) * 4;
    const int ar = tid / 4;
    const int ac = (tid % 4) * 4;
    const int br = tid / 16;
    const int bc = (tid % 16) * 4;
    const int b0 = ar >> 1;
    const int so = ar & 1;

    for (int i = 0; i < 16; ++i) {
      const int j = (i << 8) + bw;
      const int st = j >> 4;         // s-tile (2 steps)
      const int ct = j & 15;         // col-tile (64 cols)
      const int s2 = 2 * st + so;

      float acc[8][4] = {};
      for (int k0 = 0; k0 < NIN; k0 += 16) {
        float4 av0 = *(const float4*)&x[((size_t)b0 * SEQ + s2) * NIN + k0 + ac];
        float4 av1 =
            *(const float4*)&x[((size_t)(b0 + 32) * SEQ + s2) * NIN + k0 + ac];
        As[(ac + 0) * 132 + ar] = av0.x;  As[(ac + 0) * 132 + ar + 64] = av1.x;
        As[(ac + 1) * 132 + ar] = av0.y;  As[(ac + 1) * 132 + ar + 64] = av1.y;
        As[(ac + 2) * 132 + ar] = av0.z;  As[(ac + 2) * 132 + ar + 64] = av1.z;
        As[(ac + 3) * 132 + ar] = av0.w;  As[(ac + 3) * 132 + ar + 64] = av1.w;
        float4 bv = *(const float4*)&Wi[(size_t)(k0 + br) * NHID + ct * 64 + bc];
        *(float4*)&Bs[br * 68 + bc] = bv;
        __syncthreads();

#pragma unroll
        for (int k = 0; k < 16; ++k) {
          float4 a0 = *(const float4*)&As[k * 132 + tm];
          float4 a1 = *(const float4*)&As[k * 132 + tm + 4];
          float4 b4 = *(const float4*)&Bs[k * 68 + tn];
          float ae[8] = {a0.x, a0.y, a0.z, a0.w, a1.x, a1.y, a1.z, a1.w};
          float be[4] = {b4.x, b4.y, b4.z, b4.w};
#pragma unroll
          for (int ii = 0; ii < 8; ++ii)
#pragma unroll
            for (int jj = 0; jj < 4; ++jj)
              acc[ii][jj] = fmaf(ae[ii], be[jj], acc[ii][jj]);
        }
        __syncthreads();
      }

      const float4 bb = *(const float4*)&bi[ct * 64 + tn];
#pragma unroll
      for (int r = 0; r < 8; ++r) {
        const int row = tm + r;
        const int b = row >> 1;
        const int s = 2 * st + (row & 1);
        f32x4 o;
        o[0] = acc[r][0] + bb.x;
        o[1] = acc[r][1] + bb.y;
        o[2] = acc[r][2] + bb.z;
        o[3] = acc[r][3] + bb.w;
        float* cp = xi + ((size_t)b * SEQ + s) * NHID + ct * 64 + tn;
        asm volatile("global_store_dwordx4 %0, %1, off sc0 sc1"
                     :: "v"(cp), "v"(o) : "memory");
      }
      // RACE FIX: drain THIS wave's asm stores to the coherence point.
      // (Compiler's barrier waitcnt does not count inline-asm stores.)
      asm volatile("s_waitcnt vmcnt(0)" ::: "memory");
      __builtin_amdgcn_sched_barrier(0);
      __syncthreads();  // all waves drained
      if (tid == 0) atomicAdd(&xi_done[st], 1u);
      __syncthreads();  // don't start overwriting As/Bs mid-signal
    }
    return;
  }

  // ================= scan (r12 body + gating + setprio) =================
  __builtin_amdgcn_s_setprio(1);
  float* hs = smem;          // 32 KB staged h
  float* P  = smem + 8192;   // 32 KB partials

  const int bg   = blockIdx.x & 7;
  const int jc   = blockIdx.x >> 3;
  const int c4   = tid & 7;
  const int kseg = tid >> 3;
  const int colbase = jc * 32 + c4 * 4;
  const int hswz  = (kseg & 7) << 2;
  const int stswz = ((tid >> 3) & 7) << 2;
  const int ob   = tid >> 5;
  const int ocol = tid & 31;
  const int oc4  = ocol >> 2;
  const int oce  = ocol & 3;

  float4 w[32];
#pragma unroll
  for (int kk = 0; kk < 32; ++kk)
    w[kk] = *(const float4*)&Wh[(size_t)(kseg * 32 + kk) * NHID + colbase];

  float* const xrow_base =
      xi + (size_t)(bg * BPERG + ob) * SEQ * NHID + jc * 32 + ocol;
  unsigned int* const gflags = flags + bg * 32;
  unsigned int* const myflag = gflags + jc;

  // prologue: wait for xi tile 0 (steps 0,1)
  if (tid < 64) {
    while (__hip_atomic_load(xi_done, __ATOMIC_RELAXED,
                             __HIP_MEMORY_SCOPE_AGENT) < 16u)
      __builtin_amdgcn_s_sleep(1);
  }
  __syncthreads();

  for (int s = 0; s < SEQ; ++s) {
    float* prow = xrow_base + (size_t)s * NHID;
    const float xin = __hip_atomic_load(prow, __ATOMIC_RELAXED,
                                        __HIP_MEMORY_SCOPE_AGENT);

    float4 acc[BPERG];
#pragma unroll
    for (int b = 0; b < BPERG; ++b) acc[b] = make_float4(0.f, 0.f, 0.f, 0.f);

    if (s > 0) {
      const float* base =
          xi + (size_t)(bg * BPERG) * SEQ * NHID + (size_t)(s - 1) * NHID + tid * 4;
#pragma unroll
      for (int b = 0; b < BPERG; ++b) {
        float4 v = *(const float4*)(base + (size_t)b * SEQ * NHID);
        *(float4*)&hs[b * NHID + ((tid * 4) ^ stswz)] = v;
      }
      __syncthreads();

#pragma unroll
      for (int b = 0; b < BPERG; ++b) {
#pragma unroll
        for (int kq = 0; kq < 8; ++kq) {
          const float4 h4 =
              *(const float4*)&hs[b * NHID + kseg * 32 + ((kq * 4) ^ hswz)];
          FMA4(h4.x, w[kq * 4 + 0], acc[b]);
          FMA4(h4.y, w[kq * 4 + 1], acc[b]);
          FMA4(h4.z, w[kq * 4 + 2], acc[b]);
          FMA4(h4.w, w[kq * 4 + 3], acc[b]);
        }
      }
    }

    {
      const int u = kseg * 8 + c4;
      const int sw = (((kseg & 7) ^ c4)) << 2;
#pragma unroll
      for (int b = 0; b < BPERG; ++b)
        *(float4*)&P[u * 32 + ((b * 4) ^ sw)] = acc[b];
    }
    __syncthreads();

    float sum = 0.f;
#pragma unroll
    for (int q = 0; q < 32; ++q) {
      const int uu = q * 8 + oc4;
      const int sw2 = ((q & 7) ^ oc4) << 2;
      sum += P[uu * 32 + ((ob * 4 + oce) ^ sw2)];
    }

    const float hn = fmaxf(tanhf(xin + sum), 0.f);
    __hip_atomic_store(prow, hn, __ATOMIC_RELAXED, __HIP_MEMORY_SCOPE_AGENT);

    __syncthreads();
    const unsigned int target = (unsigned int)(s + 1);
    if (tid == 0)
      __hip_atomic_store(myflag, target, __ATOMIC_RELAXED,
                         __HIP_MEMORY_SCOPE_AGENT);

    // poll: lanes 0-31 group flags; lanes 32-63 next xi tile readiness
    if (tid < 64) {
      const int nxt = s + 1;
      const int tile = (nxt < SEQ) ? (nxt >> 1) : 0;
      const unsigned int thr =
          (tid < 32) ? target : ((nxt < SEQ) ? 16u : 0u);
      const unsigned int* pp =
          (tid < 32) ? (gflags + tid) : (xi_done + tile);
      while (true) {
        unsigned int v = __hip_atomic_load(pp, __ATOMIC_RELAXED,
                                           __HIP_MEMORY_SCOPE_AGENT);
        if (__all(v >= thr)) break;
        __builtin_amdgcn_s_sleep(1);
      }
    }
    __syncthreads();
  }
}

extern "C" void kernel_launch(void* const* d_in, const int* in_sizes, int n_in,
                              void* d_out, int out_size, void* d_ws, size_t ws_size,
                              hipStream_t stream) {
  const float* x  = (const float*)d_in[0];  // [64,512,512]
  const float* Wi = (const float*)d_in[1];  // [512,1024]
  const float* bi = (const float*)d_in[2];  // [1024]
  const float* Wh = (const float*)d_in[3];  // [1024,1024]
  const float* Wo = (const float*)d_in[4];  // [1024,512]
  const float* bo = (const float*)d_in[5];  // [512]
  float* out = (float*)d_out;               // [64,512,512]
  float* xi  = (float*)d_ws;                // [64,512,1024] = 128 MB scratch

  // d_out head: flags[256] + xi_done[256] (2 KB); overwritten by out-GEMM.
  unsigned int* flags = (unsigned int*)d_out;

  const int M = BATCH * SEQ;  // 32768

  dim3 blk(256);
  hipMemsetAsync(flags, 0, 2048, stream);

  // Deterministic path choice: occupancy query (same answer every call —
  // correctness run, graph capture, and replay all take the same branch).
  int occ = 0;
  hipError_t qerr = hipOccupancyMaxActiveBlocksPerMultiprocessor(
      &occ, (const void*)rnn_fused, 256, 0);
  bool fused_ok = (qerr == hipSuccess) && (occ >= 2);

  if (fused_ok) {
    const float* Wh_p = Wh;
    const float* Wi_p = Wi;
    const float* x_p  = x;
    const float* bi_p = bi;
    float* xi_p = xi;
    unsigned int* flags_p = flags;
    void* args[6] = {(void*)&Wh_p, (void*)&Wi_p, (void*)&x_p,
                     (void*)&bi_p, (void*)&xi_p, (void*)&flags_p};
    hipError_t err = hipLaunchCooperativeKernel(
        (const void*)rnn_fused, dim3(GROUPS * BPG + 256), dim3(256), args, 0,
        stream);
    fused_ok = (err == hipSuccess);
  }

  if (!fused_ok) {
    // FALLBACK: proven r12 three-kernel sequence.
    gemm_bias<<<dim3(NHID / BN, M / BM), blk, 0, stream>>>(x, Wi, bi, xi, M,
                                                           NHID, NIN);
    const float* Wh_p = Wh;
    float* xi_p = xi;
    unsigned int* flags_p = flags;
    void* args[3] = {(void*)&Wh_p, (void*)&xi_p, (void*)&flags_p};
    hipLaunchCooperativeKernel((const void*)rnn_scan_ws, dim3(GROUPS * BPG),
                               dim3(256), args, 0, stream);
  }

  // y = h @ Wo + bo  (bf16 MFMA, fp32 accumulate)
  gemm_bias_bf16<<<dim3(NOUT / OBN, M / OBM), blk, 0, stream>>>(xi, Wo, bo, out,
                                                               M, NOUT, NHID);
}

// Round 16
// 2414.136 us; speedup vs baseline: 1.7611x; 1.0217x over previous
//
#include <hip/hip_runtime.h>
#include <math.h>

// Sizes (fixed by the problem)
#define BATCH   64
#define SEQ     512
#define NIN     512
#define NHID    1024
#define NOUT    512

typedef short short8 __attribute__((ext_vector_type(8)));
typedef float f32x4 __attribute__((ext_vector_type(4)));

// RNE fp32 -> bf16 bits
__device__ __forceinline__ unsigned short f2bf(float f) {
  unsigned int u = __float_as_uint(f);
  unsigned int r = (u + 0x7fffu + ((u >> 16) & 1u)) >> 16;
  return (unsigned short)r;
}

#define GROUPS 8
#define BPG    32
#define BPERG  8

#define FMA4(hv, wv4, accv)              \
  accv.x = fmaf(hv, wv4.x, accv.x);      \
  accv.y = fmaf(hv, wv4.y, accv.y);      \
  accv.z = fmaf(hv, wv4.z, accv.z);      \
  accv.w = fmaf(hv, wv4.w, accv.w);

// ---------------- Tiled fp32 GEMM with bias (FALLBACK xi path) ----------
#define BM 128
#define BN 64
#define BK 16

__global__ __launch_bounds__(256) void gemm_bias(
    const float* __restrict__ A, const float* __restrict__ B,
    const float* __restrict__ bias, float* __restrict__ C,
    int M, int N, int K) {
  __shared__ float As[BK][BM + 4];
  __shared__ float Bs[BK][BN + 4];

  const int tid = threadIdx.x;
  const int bx = blockIdx.x;
  const int by = blockIdx.y;

  const int tm = (tid / 16) * 8;
  const int tn = (tid % 16) * 4;

  const int ar = tid / 4;
  const int ac = (tid % 4) * 4;
  const int br = tid / 16;
  const int bc = (tid % 16) * 4;

  float acc[8][4] = {};

  for (int k0 = 0; k0 < K; k0 += BK) {
    float4 av0 = *(const float4*)&A[(size_t)(by * BM + ar) * K + k0 + ac];
    float4 av1 = *(const float4*)&A[(size_t)(by * BM + ar + 64) * K + k0 + ac];
    As[ac + 0][ar] = av0.x;  As[ac + 0][ar + 64] = av1.x;
    As[ac + 1][ar] = av0.y;  As[ac + 1][ar + 64] = av1.y;
    As[ac + 2][ar] = av0.z;  As[ac + 2][ar + 64] = av1.z;
    As[ac + 3][ar] = av0.w;  As[ac + 3][ar + 64] = av1.w;
    float4 bv = *(const float4*)&B[(size_t)(k0 + br) * N + bx * BN + bc];
    *(float4*)&Bs[br][bc] = bv;
    __syncthreads();

#pragma unroll
    for (int k = 0; k < BK; ++k) {
      float4 a0 = *(const float4*)&As[k][tm];
      float4 a1 = *(const float4*)&As[k][tm + 4];
      float4 b4 = *(const float4*)&Bs[k][tn];
      float ae[8] = {a0.x, a0.y, a0.z, a0.w, a1.x, a1.y, a1.z, a1.w};
      float be[4] = {b4.x, b4.y, b4.z, b4.w};
#pragma unroll
      for (int i = 0; i < 8; ++i)
#pragma unroll
        for (int j = 0; j < 4; ++j)
          acc[i][j] = fmaf(ae[i], be[j], acc[i][j]);
    }
    __syncthreads();
  }

  const float4 bb = *(const float4*)&bias[bx * BN + tn];
#pragma unroll
  for (int i = 0; i < 8; ++i) {
    float4 o;
    o.x = acc[i][0] + bb.x;
    o.y = acc[i][1] + bb.y;
    o.z = acc[i][2] + bb.z;
    o.w = acc[i][3] + bb.w;
    *(float4*)&C[(size_t)(by * BM + tm + i) * N + bx * BN + tn] = o;
  }
}

// ---------------- bf16 MFMA GEMM with bias (output projection) ----------
// r16: B-staging rewritten to kill the 32-way LDS write conflict (was 53M
// conflicts): lane owns n = 32*jj + (tid&31) (row-stride-1 across lanes ->
// ~4-way), scalar coalesced global loads, k-pairs packed into b32 writes.
// LDS layout & fragment reads unchanged (validated r9/r12/r15).
#define OBM 128
#define OBN 128
#define OBK 32
#define LDK 40

__global__ __launch_bounds__(256) void gemm_bias_bf16(
    const float* __restrict__ A, const float* __restrict__ B,
    const float* __restrict__ bias, float* __restrict__ C,
    int M, int N, int K) {
  __shared__ unsigned short Asb[OBM][LDK];
  __shared__ unsigned short Bsb[OBN][LDK];

  const int tid  = threadIdx.x;
  const int lane = tid & 63;
  const int wid  = tid >> 6;
  const int wm   = wid >> 1;
  const int wn   = wid & 1;
  const int bx   = blockIdx.x;
  const int by   = blockIdx.y;

  const int ar  = tid >> 1;
  const int aks = (tid & 1) * 16;
  const int bk4 = (tid >> 5) * 4;   // 4 k values per thread
  const int tb  = tid & 31;         // n-within-32 (lane-consecutive)

  const int l15 = lane & 15;
  const int lk8 = (lane >> 4) * 8;

  f32x4 acc[4][4];
#pragma unroll
  for (int i = 0; i < 4; ++i)
#pragma unroll
    for (int j = 0; j < 4; ++j) acc[i][j] = (f32x4){0.f, 0.f, 0.f, 0.f};

  for (int k0 = 0; k0 < K; k0 += OBK) {
    const float* Ap = &A[(size_t)(by * OBM + ar) * K + k0 + aks];
    float4 a0 = *(const float4*)(Ap + 0);
    float4 a1 = *(const float4*)(Ap + 4);
    float4 a2 = *(const float4*)(Ap + 8);
    float4 a3 = *(const float4*)(Ap + 12);
    unsigned short ta[16] = {
        f2bf(a0.x), f2bf(a0.y), f2bf(a0.z), f2bf(a0.w),
        f2bf(a1.x), f2bf(a1.y), f2bf(a1.z), f2bf(a1.w),
        f2bf(a2.x), f2bf(a2.y), f2bf(a2.z), f2bf(a2.w),
        f2bf(a3.x), f2bf(a3.y), f2bf(a3.z), f2bf(a3.w)};
    *(short8*)&Asb[ar][aks + 0] = *(short8*)&ta[0];
    *(short8*)&Asb[ar][aks + 8] = *(short8*)&ta[8];

    // B staging: scalar coalesced loads; b32 writes at ~4-way conflict.
    float bvv[4][4];
#pragma unroll
    for (int kk = 0; kk < 4; ++kk)
#pragma unroll
      for (int jj = 0; jj < 4; ++jj)
        bvv[kk][jj] =
            B[(size_t)(k0 + bk4 + kk) * N + bx * OBN + jj * 32 + tb];
#pragma unroll
    for (int jj = 0; jj < 4; ++jj)
#pragma unroll
      for (int kk = 0; kk < 4; kk += 2) {
        unsigned int pk = (unsigned int)f2bf(bvv[kk][jj]) |
                          ((unsigned int)f2bf(bvv[kk + 1][jj]) << 16);
        *(unsigned int*)&Bsb[jj * 32 + tb][bk4 + kk] = pk;
      }
    __syncthreads();

    short8 afr[4], bfr[4];
#pragma unroll
    for (int t = 0; t < 4; ++t) {
      afr[t] = *(const short8*)&Asb[wm * 64 + t * 16 + l15][lk8];
      bfr[t] = *(const short8*)&Bsb[wn * 64 + t * 16 + l15][lk8];
    }
#pragma unroll
    for (int rt = 0; rt < 4; ++rt)
#pragma unroll
      for (int ct = 0; ct < 4; ++ct)
        acc[rt][ct] = __builtin_amdgcn_mfma_f32_16x16x32_bf16(
            afr[rt], bfr[ct], acc[rt][ct], 0, 0, 0);
    __syncthreads();
  }

#pragma unroll
  for (int rt = 0; rt < 4; ++rt) {
    const int row0 = by * OBM + wm * 64 + rt * 16 + (lane >> 4) * 4;
#pragma unroll
    for (int ct = 0; ct < 4; ++ct) {
      const int col = bx * OBN + wn * 64 + ct * 16 + l15;
      const float bb = bias[col];
#pragma unroll
      for (int i = 0; i < 4; ++i)
        C[(size_t)(row0 + i) * N + col] = acc[rt][ct][i] + bb;
    }
  }
}

// ---------------- FALLBACK scan (r12 verbatim, proven 1.95 ms) ----------
__global__ __launch_bounds__(256, 1) void rnn_scan_ws(
    const float* __restrict__ Wh, float* __restrict__ xi,
    unsigned int* flags) {
  __shared__ float hs[BPERG * NHID];
  __shared__ float P[256 * 32];

  const int tid  = threadIdx.x;
  const int bg   = blockIdx.x & 7;
  const int jc   = blockIdx.x >> 3;
  const int c4   = tid & 7;
  const int kseg = tid >> 3;
  const int colbase = jc * 32 + c4 * 4;
  const int hswz  = (kseg & 7) << 2;
  const int stswz = ((tid >> 3) & 7) << 2;
  const int ob   = tid >> 5;
  const int ocol = tid & 31;
  const int oc4  = ocol >> 2;
  const int oce  = ocol & 3;

  float4 w[32];
#pragma unroll
  for (int kk = 0; kk < 32; ++kk)
    w[kk] = *(const float4*)&Wh[(size_t)(kseg * 32 + kk) * NHID + colbase];

  float* const xrow_base =
      xi + (size_t)(bg * BPERG + ob) * SEQ * NHID + jc * 32 + ocol;
  unsigned int* const gflags = flags + bg * 32;
  unsigned int* const myflag = gflags + jc;
  unsigned int* const pollflag = gflags + (tid & 31);

  float xin = __hip_atomic_load(xrow_base, __ATOMIC_RELAXED,
                                __HIP_MEMORY_SCOPE_AGENT);

  for (int s = 0; s < SEQ; ++s) {
    float* prow = xrow_base + (size_t)s * NHID;

    float4 acc[BPERG];
#pragma unroll
    for (int b = 0; b < BPERG; ++b) acc[b] = make_float4(0.f, 0.f, 0.f, 0.f);

    if (s > 0) {
      const float* base =
          xi + (size_t)(bg * BPERG) * SEQ * NHID + (size_t)(s - 1) * NHID + tid * 4;
#pragma unroll
      for (int b = 0; b < BPERG; ++b) {
        float4 v = *(const float4*)(base + (size_t)b * SEQ * NHID);
        *(float4*)&hs[b * NHID + ((tid * 4) ^ stswz)] = v;
      }
      __syncthreads();

#pragma unroll
      for (int b = 0; b < BPERG; ++b) {
#pragma unroll
        for (int kq = 0; kq < 8; ++kq) {
          const float4 h4 =
              *(const float4*)&hs[b * NHID + kseg * 32 + ((kq * 4) ^ hswz)];
          FMA4(h4.x, w[kq * 4 + 0], acc[b]);
          FMA4(h4.y, w[kq * 4 + 1], acc[b]);
          FMA4(h4.z, w[kq * 4 + 2], acc[b]);
          FMA4(h4.w, w[kq * 4 + 3], acc[b]);
        }
      }
    }

    {
      const int u = kseg * 8 + c4;
      const int sw = (((kseg & 7) ^ c4)) << 2;
#pragma unroll
      for (int b = 0; b < BPERG; ++b)
        *(float4*)&P[u * 32 + ((b * 4) ^ sw)] = acc[b];
    }
    __syncthreads();

    float sum = 0.f;
#pragma unroll
    for (int q = 0; q < 32; ++q) {
      const int uu = q * 8 + oc4;
      const int sw2 = ((q & 7) ^ oc4) << 2;
      sum += P[uu * 32 + ((ob * 4 + oce) ^ sw2)];
    }

    const float hn = fmaxf(tanhf(xin + sum), 0.f);
    __hip_atomic_store(prow, hn, __ATOMIC_RELAXED, __HIP_MEMORY_SCOPE_AGENT);

    __syncthreads();
    const unsigned int target = (unsigned int)(s + 1);
    if (tid == 0)
      __hip_atomic_store(myflag, target, __ATOMIC_RELAXED,
                         __HIP_MEMORY_SCOPE_AGENT);

    if (s + 1 < SEQ)
      xin = __hip_atomic_load(xrow_base + (size_t)(s + 1) * NHID,
                              __ATOMIC_RELAXED, __HIP_MEMORY_SCOPE_AGENT);

    if (tid < 64) {
      while (true) {
        unsigned int v = __hip_atomic_load(pollflag, __ATOMIC_RELAXED,
                                           __HIP_MEMORY_SCOPE_AGENT);
        if (__all(v >= target)) break;
        __builtin_amdgcn_s_sleep(1);
      }
    }
    __syncthreads();
  }
}

// ---------------- FUSED: scan (blocks 0..255) + xi workers (256..511) ---
// r15-proven structure + WORKER PACING: sweep i gated on all-groups scan
// progress >= 32*(i-2) steps (2-sweep slack). Spreads the worker burst
// (~220 us) evenly over the scan (~2 ms) -> ~11% duty cycle instead of a
// front-loaded collision with the scan's critical path. Deadlock-free by
// induction: scan reaching 32(i-2) needs only sweeps <= i-2, whose gates
// are strictly lower.
__global__ __launch_bounds__(256, 2) void rnn_fused(
    const float* __restrict__ Wh, const float* __restrict__ Wi,
    const float* __restrict__ x, const float* __restrict__ bi,
    float* __restrict__ xi, unsigned int* flags) {
  __shared__ float smem[16384];  // 64 KB, role-dependent layout
  const int tid = threadIdx.x;
  unsigned int* const xi_done = flags + 256;

  if (blockIdx.x >= GROUPS * BPG) {
    // ================= worker =================
    const int bw = blockIdx.x - GROUPS * BPG;  // 0..255
    float* As = smem;                // [16][132]
    float* Bs = smem + 16 * 132;     // [16][68]
    const int tm = (tid / 16) * 8;
    const int tn = (tid % 16) * 4;
    const int ar = tid / 4;
    const int ac = (tid % 4) * 4;
    const int br = tid / 16;
    const int bc = (tid % 16) * 4;
    const int b0 = ar >> 1;
    const int so = ar & 1;

    for (int i = 0; i < 16; ++i) {
      // ---- pacing gate: stay <=2 sweeps ahead of the slowest group ----
      if (i >= 3) {
        const unsigned int thr = (unsigned int)(32 * (i - 2));
        if (tid < 64) {
          const unsigned int* pf = flags + ((tid & 7) << 5);  // group g, jc=0
          while (true) {
            unsigned int v = __hip_atomic_load(pf, __ATOMIC_RELAXED,
                                               __HIP_MEMORY_SCOPE_AGENT);
            if (__all(v >= thr)) break;
            __builtin_amdgcn_s_sleep(32);
          }
        }
        __syncthreads();
      }

      const int j = (i << 8) + bw;
      const int st = j >> 4;         // s-tile (2 steps)
      const int ct = j & 15;         // col-tile (64 cols)
      const int s2 = 2 * st + so;

      float acc[8][4] = {};
      for (int k0 = 0; k0 < NIN; k0 += 16) {
        float4 av0 = *(const float4*)&x[((size_t)b0 * SEQ + s2) * NIN + k0 + ac];
        float4 av1 =
            *(const float4*)&x[((size_t)(b0 + 32) * SEQ + s2) * NIN + k0 + ac];
        As[(ac + 0) * 132 + ar] = av0.x;  As[(ac + 0) * 132 + ar + 64] = av1.x;
        As[(ac + 1) * 132 + ar] = av0.y;  As[(ac + 1) * 132 + ar + 64] = av1.y;
        As[(ac + 2) * 132 + ar] = av0.z;  As[(ac + 2) * 132 + ar + 64] = av1.z;
        As[(ac + 3) * 132 + ar] = av0.w;  As[(ac + 3) * 132 + ar + 64] = av1.w;
        float4 bv = *(const float4*)&Wi[(size_t)(k0 + br) * NHID + ct * 64 + bc];
        *(float4*)&Bs[br * 68 + bc] = bv;
        __syncthreads();

#pragma unroll
        for (int k = 0; k < 16; ++k) {
          float4 a0 = *(const float4*)&As[k * 132 + tm];
          float4 a1 = *(const float4*)&As[k * 132 + tm + 4];
          float4 b4 = *(const float4*)&Bs[k * 68 + tn];
          float ae[8] = {a0.x, a0.y, a0.z, a0.w, a1.x, a1.y, a1.z, a1.w};
          float be[4] = {b4.x, b4.y, b4.z, b4.w};
#pragma unroll
          for (int ii = 0; ii < 8; ++ii)
#pragma unroll
            for (int jj = 0; jj < 4; ++jj)
              acc[ii][jj] = fmaf(ae[ii], be[jj], acc[ii][jj]);
        }
        __syncthreads();
      }

      const float4 bb = *(const float4*)&bi[ct * 64 + tn];
#pragma unroll
      for (int r = 0; r < 8; ++r) {
        const int row = tm + r;
        const int b = row >> 1;
        const int s = 2 * st + (row & 1);
        f32x4 o;
        o[0] = acc[r][0] + bb.x;
        o[1] = acc[r][1] + bb.y;
        o[2] = acc[r][2] + bb.z;
        o[3] = acc[r][3] + bb.w;
        float* cp = xi + ((size_t)b * SEQ + s) * NHID + ct * 64 + tn;
        asm volatile("global_store_dwordx4 %0, %1, off sc0 sc1"
                     :: "v"(cp), "v"(o) : "memory");
      }
      // Drain THIS wave's asm stores (compiler doesn't track them) before
      // signaling.
      asm volatile("s_waitcnt vmcnt(0)" ::: "memory");
      __builtin_amdgcn_sched_barrier(0);
      __syncthreads();  // all waves drained
      if (tid == 0) atomicAdd(&xi_done[st], 1u);
      __syncthreads();
    }
    return;
  }

  // ================= scan (r12 body + gating + setprio) =================
  __builtin_amdgcn_s_setprio(1);
  float* hs = smem;          // 32 KB staged h
  float* P  = smem + 8192;   // 32 KB partials

  const int bg   = blockIdx.x & 7;
  const int jc   = blockIdx.x >> 3;
  const int c4   = tid & 7;
  const int kseg = tid >> 3;
  const int colbase = jc * 32 + c4 * 4;
  const int hswz  = (kseg & 7) << 2;
  const int stswz = ((tid >> 3) & 7) << 2;
  const int ob   = tid >> 5;
  const int ocol = tid & 31;
  const int oc4  = ocol >> 2;
  const int oce  = ocol & 3;

  float4 w[32];
#pragma unroll
  for (int kk = 0; kk < 32; ++kk)
    w[kk] = *(const float4*)&Wh[(size_t)(kseg * 32 + kk) * NHID + colbase];

  float* const xrow_base =
      xi + (size_t)(bg * BPERG + ob) * SEQ * NHID + jc * 32 + ocol;
  unsigned int* const gflags = flags + bg * 32;
  unsigned int* const myflag = gflags + jc;

  // prologue: wait for xi tile 0 (steps 0,1)
  if (tid < 64) {
    while (__hip_atomic_load(xi_done, __ATOMIC_RELAXED,
                             __HIP_MEMORY_SCOPE_AGENT) < 16u)
      __builtin_amdgcn_s_sleep(1);
  }
  __syncthreads();

  for (int s = 0; s < SEQ; ++s) {
    float* prow = xrow_base + (size_t)s * NHID;
    const float xin = __hip_atomic_load(prow, __ATOMIC_RELAXED,
                                        __HIP_MEMORY_SCOPE_AGENT);

    float4 acc[BPERG];
#pragma unroll
    for (int b = 0; b < BPERG; ++b) acc[b] = make_float4(0.f, 0.f, 0.f, 0.f);

    if (s > 0) {
      const float* base =
          xi + (size_t)(bg * BPERG) * SEQ * NHID + (size_t)(s - 1) * NHID + tid * 4;
#pragma unroll
      for (int b = 0; b < BPERG; ++b) {
        float4 v = *(const float4*)(base + (size_t)b * SEQ * NHID);
        *(float4*)&hs[b * NHID + ((tid * 4) ^ stswz)] = v;
      }
      __syncthreads();

#pragma unroll
      for (int b = 0; b < BPERG; ++b) {
#pragma unroll
        for (int kq = 0; kq < 8; ++kq) {
          const float4 h4 =
              *(const float4*)&hs[b * NHID + kseg * 32 + ((kq * 4) ^ hswz)];
          FMA4(h4.x, w[kq * 4 + 0], acc[b]);
          FMA4(h4.y, w[kq * 4 + 1], acc[b]);
          FMA4(h4.z, w[kq * 4 + 2], acc[b]);
          FMA4(h4.w, w[kq * 4 + 3], acc[b]);
        }
      }
    }

    {
      const int u = kseg * 8 + c4;
      const int sw = (((kseg & 7) ^ c4)) << 2;
#pragma unroll
      for (int b = 0; b < BPERG; ++b)
        *(float4*)&P[u * 32 + ((b * 4) ^ sw)] = acc[b];
    }
    __syncthreads();

    float sum = 0.f;
#pragma unroll
    for (int q = 0; q < 32; ++q) {
      const int uu = q * 8 + oc4;
      const int sw2 = ((q & 7) ^ oc4) << 2;
      sum += P[uu * 32 + ((ob * 4 + oce) ^ sw2)];
    }

    const float hn = fmaxf(tanhf(xin + sum), 0.f);
    __hip_atomic_store(prow, hn, __ATOMIC_RELAXED, __HIP_MEMORY_SCOPE_AGENT);

    __syncthreads();
    const unsigned int target = (unsigned int)(s + 1);
    if (tid == 0)
      __hip_atomic_store(myflag, target, __ATOMIC_RELAXED,
                         __HIP_MEMORY_SCOPE_AGENT);

    // poll: lanes 0-31 group flags; lanes 32-63 next xi tile readiness
    if (tid < 64) {
      const int nxt = s + 1;
      const int tile = (nxt < SEQ) ? (nxt >> 1) : 0;
      const unsigned int thr =
          (tid < 32) ? target : ((nxt < SEQ) ? 16u : 0u);
      const unsigned int* pp =
          (tid < 32) ? (gflags + tid) : (xi_done + tile);
      while (true) {
        unsigned int v = __hip_atomic_load(pp, __ATOMIC_RELAXED,
                                           __HIP_MEMORY_SCOPE_AGENT);
        if (__all(v >= thr)) break;
        __builtin_amdgcn_s_sleep(1);
      }
    }
    __syncthreads();
  }
}

extern "C" void kernel_launch(void* const* d_in, const int* in_sizes, int n_in,
                              void* d_out, int out_size, void* d_ws, size_t ws_size,
                              hipStream_t stream) {
  const float* x  = (const float*)d_in[0];  // [64,512,512]
  const float* Wi = (const float*)d_in[1];  // [512,1024]
  const float* bi = (const float*)d_in[2];  // [1024]
  const float* Wh = (const float*)d_in[3];  // [1024,1024]
  const float* Wo = (const float*)d_in[4];  // [1024,512]
  const float* bo = (const float*)d_in[5];  // [512]
  float* out = (float*)d_out;               // [64,512,512]
  float* xi  = (float*)d_ws;                // [64,512,1024] = 128 MB scratch

  // d_out head: flags[256] + xi_done[256] (2 KB); overwritten by out-GEMM.
  unsigned int* flags = (unsigned int*)d_out;

  const int M = BATCH * SEQ;  // 32768

  dim3 blk(256);
  hipMemsetAsync(flags, 0, 2048, stream);

  // Deterministic path choice: occupancy query (same answer every call).
  int occ = 0;
  hipError_t qerr = hipOccupancyMaxActiveBlocksPerMultiprocessor(
      &occ, (const void*)rnn_fused, 256, 0);
  bool fused_ok = (qerr == hipSuccess) && (occ >= 2);

  if (fused_ok) {
    const float* Wh_p = Wh;
    const float* Wi_p = Wi;
    const float* x_p  = x;
    const float* bi_p = bi;
    float* xi_p = xi;
    unsigned int* flags_p = flags;
    void* args[6] = {(void*)&Wh_p, (void*)&Wi_p, (void*)&x_p,
                     (void*)&bi_p, (void*)&xi_p, (void*)&flags_p};
    hipError_t err = hipLaunchCooperativeKernel(
        (const void*)rnn_fused, dim3(GROUPS * BPG + 256), dim3(256), args, 0,
        stream);
    fused_ok = (err == hipSuccess);
  }

  if (!fused_ok) {
    // FALLBACK: proven r12 three-kernel sequence.
    gemm_bias<<<dim3(NHID / BN, M / BM), blk, 0, stream>>>(x, Wi, bi, xi, M,
                                                           NHID, NIN);
    const float* Wh_p = Wh;
    float* xi_p = xi;
    unsigned int* flags_p = flags;
    void* args[3] = {(void*)&Wh_p, (void*)&xi_p, (void*)&flags_p};
    hipLaunchCooperativeKernel((const void*)rnn_scan_ws, dim3(GROUPS * BPG),
                               dim3(256), args, 0, stream);
  }

  // y = h @ Wo + bo  (bf16 MFMA, fp32 accumulate)
  gemm_bias_bf16<<<dim3(NOUT / OBN, M / OBM), blk, 0, stream>>>(xi, Wo, bo, out,
                                                               M, NOUT, NHID);
}